// Round 7
// baseline (268.858 us; speedup 1.0000x reference)
//
#include <hip/hip_runtime.h>

#define B_ 16384
#define D_ 2048
#define P_ 64
#define K_ 5

#define BK 64
#define NCH (D_ / BK)  // 32
#define LDR 72         // LDS row stride in halves (64 + 8 pad)
#define SPLIT_SC 2048.0f
#define SPLIT_INV (1.0f / 2048.0f)

typedef _Float16 half8 __attribute__((ext_vector_type(8)));
typedef float f32x4 __attribute__((ext_vector_type(4)));

// split v into hi = f16(v) and lo = f16((v - hi) * 2^11)  (scaled into f16
// normal range so MFMA denormal handling can't eat the correction term)
static __device__ __forceinline__ void split8(const float4 a, const float4 b,
                                              half8& hi, half8& lo) {
  const float v[8] = {a.x, a.y, a.z, a.w, b.x, b.y, b.z, b.w};
#pragma unroll
  for (int i = 0; i < 8; ++i) {
    const _Float16 h = (_Float16)v[i];
    hi[i] = h;
    lo[i] = (_Float16)((v[i] - (float)h) * SPLIT_SC);
  }
}

// ---------------------------------------------------------------------------
// K1: parent GEMM via split-f16 MFMA (fp32-accurate: acc_main + acc_corr/2^11),
// fully fused: logits + bias + argmax + expert row-lists.
// grid 256 x 256 thr (4 waves). Block = 64 rows x 64 cols, full D.
// Wave w owns cols 16w..16w+15; 4 m-frags of 16x16x32. Double-buffered LDS.
// HBM-bound on the one-time 134 MB x read (~21 us floor).
// ---------------------------------------------------------------------------
__global__ __launch_bounds__(256) void k1_parent(
    const float* __restrict__ x, const float* __restrict__ pW,
    const float* __restrict__ pb, float* __restrict__ pout,
    int* __restrict__ cnt, int* __restrict__ list) {
  __shared__ _Float16 xlh[2][64 * LDR], xll[2][64 * LDR];  // 18.4 KB pairs
  __shared__ _Float16 wlh[2][64 * LDR], wll[2][64 * LDR];
  __shared__ float rmax[64][4];
  __shared__ int ridx[64][4];

  const int tid = threadIdx.x;
  const int b0 = blockIdx.x * 64;
  const int w = tid >> 6;  // wave
  const int l = tid & 63;  // lane
  const int r = tid >> 2;  // staging row 0..63
  const int c = tid & 3;   // staging k-quad (16 floats)

  const float* xg = x + (size_t)(b0 + r) * D_ + c * 16;
  const float* wg = pW + (size_t)r * D_ + c * 16;
  const float bias = pb[w * 16 + (l & 15)];

  const int aoff = (l & 15) * LDR + (l >> 4) * 8;
  const int boff = (w * 16 + (l & 15)) * LDR + (l >> 4) * 8;
  const int soff = r * LDR + c * 16;

  f32x4 acc[4], accc[4];
#pragma unroll
  for (int fm = 0; fm < 4; ++fm) {
    acc[fm] = {0.f, 0.f, 0.f, 0.f};
    accc[fm] = {0.f, 0.f, 0.f, 0.f};
  }

  {  // prologue: stage chunk 0 -> buf 0
    const float4* xp = (const float4*)xg;
    const float4* wp = (const float4*)wg;
    half8 h, lo;
    split8(xp[0], xp[1], h, lo);
    *(half8*)&xlh[0][soff] = h; *(half8*)&xll[0][soff] = lo;
    split8(xp[2], xp[3], h, lo);
    *(half8*)&xlh[0][soff + 8] = h; *(half8*)&xll[0][soff + 8] = lo;
    split8(wp[0], wp[1], h, lo);
    *(half8*)&wlh[0][soff] = h; *(half8*)&wll[0][soff] = lo;
    split8(wp[2], wp[3], h, lo);
    *(half8*)&wlh[0][soff + 8] = h; *(half8*)&wll[0][soff + 8] = lo;
  }
  __syncthreads();

  for (int ch = 0; ch < NCH; ++ch) {
    const int cur = ch & 1;
    float4 x0, x1, x2, x3, w0, w1, w2, w3;
    const bool more = (ch + 1 < NCH);
    if (more) {  // issue next-chunk loads; latency hides under MFMA phase
      const float4* xp = (const float4*)(xg + (ch + 1) * BK);
      const float4* wp = (const float4*)(wg + (ch + 1) * BK);
      x0 = xp[0]; x1 = xp[1]; x2 = xp[2]; x3 = xp[3];
      w0 = wp[0]; w1 = wp[1]; w2 = wp[2]; w3 = wp[3];
    }
#pragma unroll
    for (int s = 0; s < 2; ++s) {
      const int ko = s * 32;
      const half8 bh = *(const half8*)&wlh[cur][boff + ko];
      const half8 bl = *(const half8*)&wll[cur][boff + ko];
#pragma unroll
      for (int fm = 0; fm < 4; ++fm) {
        const half8 ah = *(const half8*)&xlh[cur][aoff + fm * 16 * LDR + ko];
        const half8 al = *(const half8*)&xll[cur][aoff + fm * 16 * LDR + ko];
        acc[fm]  = __builtin_amdgcn_mfma_f32_16x16x32_f16(ah, bh, acc[fm], 0, 0, 0);
        accc[fm] = __builtin_amdgcn_mfma_f32_16x16x32_f16(ah, bl, accc[fm], 0, 0, 0);
        accc[fm] = __builtin_amdgcn_mfma_f32_16x16x32_f16(al, bh, accc[fm], 0, 0, 0);
      }
    }
    if (more) {
      const int nxt = cur ^ 1;
      half8 h, lo;
      split8(x0, x1, h, lo);
      *(half8*)&xlh[nxt][soff] = h; *(half8*)&xll[nxt][soff] = lo;
      split8(x2, x3, h, lo);
      *(half8*)&xlh[nxt][soff + 8] = h; *(half8*)&xll[nxt][soff + 8] = lo;
      split8(w0, w1, h, lo);
      *(half8*)&wlh[nxt][soff] = h; *(half8*)&wll[nxt][soff] = lo;
      split8(w2, w3, h, lo);
      *(half8*)&wlh[nxt][soff + 8] = h; *(half8*)&wll[nxt][soff + 8] = lo;
    }
    __syncthreads();
  }

  // ---- fused epilogue: combine, bias, store logits, argmax, expert lists ----
  const int colbase = w * 16 + (l & 15);
  float val[4][4];
#pragma unroll
  for (int fm = 0; fm < 4; ++fm) {
#pragma unroll
    for (int j = 0; j < 4; ++j) {
      val[fm][j] = acc[fm][j] + accc[fm][j] * SPLIT_INV + bias;
      const int row = fm * 16 + ((l >> 4) << 2) + j;  // C/D: row=(lane>>4)*4+reg
      pout[(size_t)(b0 + row) * P_ + colbase] = val[fm][j];
    }
  }
#pragma unroll
  for (int fm = 0; fm < 4; ++fm) {
#pragma unroll
    for (int j = 0; j < 4; ++j) {
      float bv = val[fm][j];
      int bi = colbase;
#pragma unroll
      for (int s = 8; s > 0; s >>= 1) {
        const float ov = __shfl_xor(bv, s, 64);
        const int oi = __shfl_xor(bi, s, 64);
        if (ov > bv || (ov == bv && oi < bi)) { bv = ov; bi = oi; }
      }
      if ((l & 15) == 0) {
        const int row = fm * 16 + ((l >> 4) << 2) + j;
        rmax[row][w] = bv;
        ridx[row][w] = bi;
      }
    }
  }
  __syncthreads();
  if (tid < 64) {
    float bv = rmax[tid][0];
    int bi = ridx[tid][0];
#pragma unroll
    for (int ww = 1; ww < 4; ++ww) {
      const float ov = rmax[tid][ww];
      const int oi = ridx[tid][ww];
      if (ov > bv || (ov == bv && oi < bi)) { bv = ov; bi = oi; }
    }
    const int slot = atomicAdd(&cnt[bi * 16], 1);  // 64B-padded counters
    if (slot < 1024) list[bi * 1024 + slot] = b0 + tid;
  }
}

// ---------------------------------------------------------------------------
// K2: child logits from dense row lists (fp32 VALU). grid = 64 experts x 4
// chunks (stages cW exactly once chip-wide). 4 rows batched per W pass;
// pair-packed butterfly reduce.
// ---------------------------------------------------------------------------
__global__ __launch_bounds__(256) void k2_child(const float* __restrict__ x,
                                                const float* __restrict__ cW,
                                                const float* __restrict__ cb,
                                                const int* __restrict__ cnt,
                                                const int* __restrict__ list,
                                                float* __restrict__ cout) {
  __shared__ float wlds[K_ * D_];  // 40 KB
  const int e = blockIdx.x >> 2;
  const int chk = blockIdx.x & 3;
  const int tid = threadIdx.x;

  const float4* wg4 = (const float4*)(cW + (size_t)e * (K_ * D_));
  float4* wl4 = (float4*)wlds;
#pragma unroll
  for (int tI = 0; tI < 10; ++tI) wl4[tid + 256 * tI] = wg4[tid + 256 * tI];
  __syncthreads();

  const int n = min(cnt[e * 16], 1024);
  const int per = (n + 3) >> 2;
  const int lo = chk * per;
  const int hi = min(lo + per, n);
  const int m = hi - lo;
  if (m <= 0) return;

  const int wave = tid >> 6, lane = tid & 63;
  const int wper = (m + 3) >> 2;
  const int wlo = lo + wave * wper;
  const int whi = min(wlo + wper, hi);

  const float4* x4 = (const float4*)x;
  const int* mylist = list + e * 1024;

  for (int i0 = wlo; i0 < whi; i0 += 4) {
    const int vb = min(4, whi - i0);
    const int ra = mylist[i0];
    const int rb = mylist[i0 + min(1, vb - 1)];
    const int rc = mylist[i0 + min(2, vb - 1)];
    const int rd = mylist[i0 + min(3, vb - 1)];

    float a[20];
#pragma unroll
    for (int q = 0; q < 20; ++q) a[q] = 0.f;

#pragma unroll
    for (int tt = 0; tt < 8; ++tt) {
      const float4 xv0 = x4[(size_t)ra * 512 + lane + 64 * tt];
      const float4 xv1 = x4[(size_t)rb * 512 + lane + 64 * tt];
      const float4 xv2 = x4[(size_t)rc * 512 + lane + 64 * tt];
      const float4 xv3 = x4[(size_t)rd * 512 + lane + 64 * tt];
#pragma unroll
      for (int k = 0; k < 5; ++k) {
        const float4 wv = wl4[k * 512 + lane + 64 * tt];
        a[0 * 5 + k] += xv0.x * wv.x + xv0.y * wv.y + xv0.z * wv.z + xv0.w * wv.w;
        a[1 * 5 + k] += xv1.x * wv.x + xv1.y * wv.y + xv1.z * wv.z + xv1.w * wv.w;
        a[2 * 5 + k] += xv2.x * wv.x + xv2.y * wv.y + xv2.z * wv.z + xv2.w * wv.w;
        a[3 * 5 + k] += xv3.x * wv.x + xv3.y * wv.y + xv3.z * wv.z + xv3.w * wv.w;
      }
    }
#pragma unroll
    for (int p = 0; p < 10; ++p) {
      float va = a[2 * p], vb2 = a[2 * p + 1];
      va += __shfl_xor(va, 32, 64);
      vb2 += __shfl_xor(vb2, 32, 64);
      float z = (lane < 32) ? va : vb2;
      z += __shfl_xor(z, 16, 64);
      z += __shfl_xor(z, 8, 64);
      z += __shfl_xor(z, 4, 64);
      z += __shfl_xor(z, 2, 64);
      z += __shfl_xor(z, 1, 64);
      a[2 * p] = z;
    }
    if (lane == 0 || lane == 32) {
      const int off = (lane == 32) ? 1 : 0;
#pragma unroll
      for (int p = 0; p < 10; ++p) {
        const int f = 2 * p + off;
        const int rr = f / 5, kk = f % 5;
        if (rr < vb) {
          const int rX = (rr == 0) ? ra : (rr == 1) ? rb : (rr == 2) ? rc : rd;
          cout[(size_t)rX * K_ + kk] = a[2 * p] + cb[e * K_ + kk];
        }
      }
    }
  }
}

extern "C" void kernel_launch(void* const* d_in, const int* in_sizes, int n_in,
                              void* d_out, int out_size, void* d_ws, size_t ws_size,
                              hipStream_t stream) {
  const float* x  = (const float*)d_in[0];
  const float* pW = (const float*)d_in[1];
  const float* pb = (const float*)d_in[2];
  const float* cW = (const float*)d_in[3];
  const float* cb = (const float*)d_in[4];
  float* pout = (float*)d_out;                    // [B, 64]
  float* cout = (float*)d_out + (size_t)B_ * P_;  // [B, 5]

  char* ws = (char*)d_ws;
  int* cnt  = (int*)ws;           // 64 counters, 64 B apart (4 KB)
  int* list = (int*)(ws + 4096);  // 64 x 1024 ints (256 KB)

  hipMemsetAsync(cnt, 0, 4096, stream);
  k1_parent<<<B_ / 64, 256, 0, stream>>>(x, pW, pb, pout, cnt, list);
  k2_child<<<P_ * 4, 256, 0, stream>>>(x, cW, cb, cnt, list, cout);
}